// Round 6
// baseline (109.411 us; speedup 1.0000x reference)
//
#include <hip/hip_runtime.h>
#include <hip/hip_bf16.h>

// CapsuleNet dynamic routing, fused per-sample. fp32 I/O:
// x: f32 [8192, 32, 8], W: f32 [32, 8, 256], out: f32 [8192, 16, 16].
// One block = 2 samples packed as the two components of v2f lanes;
// thread t = (nc = t>>4, dc = t&15) owns output column k = t.
// u_hat in registers (v2f uh2[32]); routing state in LDS.
// W pre-transposed to TWO fp32 float4 planes: WA[ic][k] = W[ic][0..3][k],
// WB[ic][k] = W[ic][4..7][k] -> two unit-stride dwordx4 loads per (ic,k),
// zero unpack instructions. Cross-lane exchanges via DPP; xor4 via ds_swizzle.

#define S 2

typedef float v2f __attribute__((ext_vector_type(2)));

// DPP cross-lane: value of `x` from lane (lane ^ k) within a 16-lane row.
// 0xB1 = quad_perm[1,0,3,2] (xor1)  0x4E = quad_perm[2,3,0,1] (xor2)
// 0x128 = row_ror:8 (xor8)  0x141 = row_half_mirror (xor7)  0x140 = row_mirror (xor15)
template <int CTRL>
__device__ __forceinline__ float dppf(float x) {
  return __builtin_bit_cast(float,
      __builtin_amdgcn_update_dpp(0, __builtin_bit_cast(int, x), CTRL, 0xF, 0xF, true));
}
template <int CTRL>
__device__ __forceinline__ v2f dpp2(v2f v) {
  v2f r;
  r.x = dppf<CTRL>(v.x);
  r.y = dppf<CTRL>(v.y);
  return r;
}
// xor4 has no DPP encoding: one ds_swizzle (BitMode: xor=4, and=0x1F)
__device__ __forceinline__ float swz4(float x) {
  return __builtin_bit_cast(float,
      __builtin_amdgcn_ds_swizzle(__builtin_bit_cast(int, x), 0x101F));
}
__device__ __forceinline__ v2f swz4_2(v2f v) {
  v2f r;
  r.x = swz4(v.x);
  r.y = swz4(v.y);
  return r;
}

// W[ic][id][k] (f32) -> two float4 planes:
// Wt[0*8192 + ic*256 + k] = {W[ic][0][k..], ids 0..3}, Wt[8192 + ...] = ids 4..7.
__global__ __launch_bounds__(256) void wt_kernel(const float* __restrict__ W,
                                                 float4* __restrict__ Wt) {
  int o     = blockIdx.x * 256 + threadIdx.x;  // 0..16383
  int plane = o >> 13;
  int ic    = (o >> 8) & 31;
  int k     = o & 255;
  const float* wp = &W[(ic * 8 + plane * 4) * 256 + k];
  float4 v;
  v.x = wp[0 * 256];
  v.y = wp[1 * 256];
  v.z = wp[2 * 256];
  v.w = wp[3 * 256];
  Wt[o] = v;
}

// squash over the 16 dc lanes, both samples at once; DPP-only reduction.
__device__ __forceinline__ v2f squash2(v2f o) {
  v2f s2 = o * o;
  s2 += dpp2<0xB1>(s2);   // + lane^1
  s2 += dpp2<0x4E>(s2);   // + lane^2
  s2 += dpp2<0x141>(s2);  // + lane^7 (row_half_mirror)
  s2 += dpp2<0x140>(s2);  // + lane^15 (row_mirror)
  s2 += (v2f){1e-7f, 1e-7f};
  v2f sc;
  sc.x = s2.x * __builtin_amdgcn_rsqf(s2.x) * __builtin_amdgcn_rcpf(1.f + s2.x);
  sc.y = s2.y * __builtin_amdgcn_rsqf(s2.y) * __builtin_amdgcn_rcpf(1.f + s2.y);
  return o * sc;  // sqrt(s2)/(1+s2) * o
}

// b[nc][ic] (=/+=) sum_dc v*uh[ic], both samples packed, via butterfly
// transpose-reduction over the 16 dc lanes; lane dc lands ic = icb + dc.
// Levels 8/2/1 via DPP, level 4 via ds_swizzle.
template <bool ASSIGN>
__device__ __forceinline__ void b_update2(v2f v, const v2f* uh2, int dc,
                                          float* bp0, float* bp1) {
#pragma unroll
  for (int icb = 0; icb < 32; icb += 16) {
    v2f a[16];
#pragma unroll
    for (int j = 0; j < 16; ++j) a[j] = v * uh2[icb + j];  // pk_mul
    v2f b8[8];
    const bool u8 = (dc & 8) != 0;
#pragma unroll
    for (int j = 0; j < 8; ++j) {
      v2f send = u8 ? a[j] : a[j + 8];
      v2f recv = dpp2<0x128>(send);          // exchange with lane^8
      b8[j] = (u8 ? a[j + 8] : a[j]) + recv;
    }
    v2f c4[4];
    const bool u4 = (dc & 4) != 0;
#pragma unroll
    for (int j = 0; j < 4; ++j) {
      v2f send = u4 ? b8[j] : b8[j + 4];
      v2f recv = swz4_2(send);               // exchange with lane^4 (DS)
      c4[j] = (u4 ? b8[j + 4] : b8[j]) + recv;
    }
    v2f d2[2];
    const bool u2 = (dc & 2) != 0;
#pragma unroll
    for (int j = 0; j < 2; ++j) {
      v2f send = u2 ? c4[j] : c4[j + 2];
      v2f recv = dpp2<0x4E>(send);           // exchange with lane^2
      d2[j] = (u2 ? c4[j + 2] : c4[j]) + recv;
    }
    const bool u1 = (dc & 1) != 0;
    v2f send = u1 ? d2[0] : d2[1];
    v2f recv = dpp2<0xB1>(send);             // exchange with lane^1
    v2f e = (u1 ? d2[1] : d2[0]) + recv;
    if (ASSIGN) { bp0[icb + dc] = e.x;  bp1[icb + dc] = e.y; }
    else        { bp0[icb + dc] += e.x; bp1[icb + dc] += e.y; }
  }
}

__global__ __launch_bounds__(256, 4) void caps_kernel(const float* __restrict__ x,
                                                      const float4* __restrict__ Wt4,
                                                      float* __restrict__ out) {
  const int t  = threadIdx.x;
  const int nc = t >> 4;
  const int dc = t & 15;
  const int s0 = blockIdx.x * S;

  __shared__ float b_lds[S][16][33];             // +1 pad: nc-column reads conflict-free
  __shared__ __align__(16) float c_lds[16][72];  // c[n][2*ic+s]; 16B-aligned rows

  v2f uh2[32];
  v2f o2 = (v2f){0.f, 0.f};

  // ---- u_hat: uh2[ic] = {sum_id u_s0*W, sum_id u_s1*W}; round-0 sum fused ----
  const v2f* xu0 = (const v2f*)(x + (s0 + 0) * 256);  // block-uniform -> s_load
  const v2f* xu1 = (const v2f*)(x + (s0 + 1) * 256);
  const float4* WA = Wt4;         // ids 0..3
  const float4* WB = Wt4 + 8192;  // ids 4..7
  float4 wa = WA[t], wb = WB[t];  // prefetch ic = 0
#pragma unroll
  for (int ic = 0; ic < 32; ++ic) {
    float4 na, nb;
    if (ic < 31) { na = WA[(ic + 1) * 256 + t]; nb = WB[(ic + 1) * 256 + t]; }
    v2f wp0 = (v2f){wa.x, wa.y};
    v2f wp1 = (v2f){wa.z, wa.w};
    v2f wp2 = (v2f){wb.x, wb.y};
    v2f wp3 = (v2f){wb.z, wb.w};
    v2f a0 = xu0[ic * 4 + 0] * wp0;  // pk_fma chain, sample 0 (id-paired)
    a0 = __builtin_elementwise_fma(xu0[ic * 4 + 1], wp1, a0);
    a0 = __builtin_elementwise_fma(xu0[ic * 4 + 2], wp2, a0);
    a0 = __builtin_elementwise_fma(xu0[ic * 4 + 3], wp3, a0);
    v2f a1 = xu1[ic * 4 + 0] * wp0;  // sample 1
    a1 = __builtin_elementwise_fma(xu1[ic * 4 + 1], wp1, a1);
    a1 = __builtin_elementwise_fma(xu1[ic * 4 + 2], wp2, a1);
    a1 = __builtin_elementwise_fma(xu1[ic * 4 + 3], wp3, a1);
    v2f u = (v2f){a0.x + a0.y, a1.x + a1.y};
    uh2[ic] = u;
    o2 += u;
    wa = na;
    wb = nb;
  }

  // ---- routing round 0: b = 0 => c = 1/16 ----
  {
    v2f v = squash2(o2 * (v2f){0.0625f, 0.0625f});
    b_update2<true>(v, uh2, dc, &b_lds[0][nc][0], &b_lds[1][nc][0]);
  }
  __syncthreads();

  // ---- rounds 1, 2 ----
#pragma unroll
  for (int r = 1; r < 3; ++r) {
    if (t < 64) {  // softmax over nc; thread (s = t>>5, ic = t&31) owns one column
      const int s = t >> 5, ic = t & 31;
      // no max-subtraction: |b| is bounded far below exp overflow, and
      // softmax is shift-invariant.
      float e[16];
      float sum = 0.f;
#pragma unroll
      for (int n = 0; n < 16; ++n) { e[n] = __expf(b_lds[s][n][ic]); sum += e[n]; }
      const float inv = __builtin_amdgcn_rcpf(sum);
#pragma unroll
      for (int n = 0; n < 16; ++n) c_lds[n][2 * ic + s] = e[n] * inv;
    }
    __syncthreads();

    const float4* cp = (const float4*)&c_lds[nc][0];  // {c0[2j],c1[2j],c0[2j+1],c1[2j+1]}
    v2f o = (v2f){0.f, 0.f};
#pragma unroll
    for (int j = 0; j < 16; ++j) {
      float4 cc = cp[j];
      o = __builtin_elementwise_fma((v2f){cc.x, cc.y}, uh2[2 * j + 0], o);
      o = __builtin_elementwise_fma((v2f){cc.z, cc.w}, uh2[2 * j + 1], o);
    }
    v2f v = squash2(o);
    if (r == 2) {
      out[(s0 + 0) * 256 + t] = v.x;
      out[(s0 + 1) * 256 + t] = v.y;
    } else {
      b_update2<false>(v, uh2, dc, &b_lds[0][nc][0], &b_lds[1][nc][0]);
      __syncthreads();  // b complete before round-2 softmax reads it
    }
  }
}

extern "C" void kernel_launch(void* const* d_in, const int* in_sizes, int n_in,
                              void* d_out, int out_size, void* d_ws, size_t ws_size,
                              hipStream_t stream) {
  const float* x = (const float*)d_in[0];
  const float* W = (const float*)d_in[1];
  float4* Wt = (float4*)d_ws;  // 256 KB scratch (fp32 W planes)

  wt_kernel<<<64, 256, 0, stream>>>(W, Wt);
  caps_kernel<<<8192 / S, 256, 0, stream>>>(x, Wt, (float*)d_out);
}

// Round 7
// 98.951 us; speedup vs baseline: 1.1057x; 1.1057x over previous
//
#include <hip/hip_runtime.h>
#include <hip/hip_bf16.h>

// CapsuleNet dynamic routing, fused per-sample. fp32 I/O:
// x: f32 [8192, 32, 8], W: f32 [32, 8, 256], out: f32 [8192, 16, 16].
// One block = 2 samples packed as the two components of v2f lanes;
// thread t = (nc = t>>4, dc = t&15) owns output column k = t.
// u_hat in registers (v2f uh2[32]); routing state in LDS.
// x and W pre-converted to f16; u_hat uses v_dot2_f32_f16 (f16 mul, f32 acc):
// per ic = one 16B W load + 8 dot2. Cross-lane via DPP; xor4 via ds_swizzle.

#define S 2

typedef float    v2f __attribute__((ext_vector_type(2)));
typedef _Float16 v2h __attribute__((ext_vector_type(2)));

// DPP cross-lane: value of `x` from lane (lane ^ k) within a 16-lane row.
// 0xB1 = quad_perm[1,0,3,2] (xor1)  0x4E = quad_perm[2,3,0,1] (xor2)
// 0x128 = row_ror:8 (xor8)  0x141 = row_half_mirror (xor7)  0x140 = row_mirror (xor15)
template <int CTRL>
__device__ __forceinline__ float dppf(float x) {
  return __builtin_bit_cast(float,
      __builtin_amdgcn_update_dpp(0, __builtin_bit_cast(int, x), CTRL, 0xF, 0xF, true));
}
template <int CTRL>
__device__ __forceinline__ v2f dpp2(v2f v) {
  v2f r;
  r.x = dppf<CTRL>(v.x);
  r.y = dppf<CTRL>(v.y);
  return r;
}
// xor4 has no DPP encoding: one ds_swizzle (BitMode: xor=4, and=0x1F)
__device__ __forceinline__ float swz4(float x) {
  return __builtin_bit_cast(float,
      __builtin_amdgcn_ds_swizzle(__builtin_bit_cast(int, x), 0x101F));
}
__device__ __forceinline__ v2f swz4_2(v2f v) {
  v2f r;
  r.x = swz4(v.x);
  r.y = swz4(v.y);
  return r;
}

#if __has_builtin(__builtin_amdgcn_fdot2)
__device__ __forceinline__ float dot2(v2h a, v2h b, float c) {
  return __builtin_amdgcn_fdot2(a, b, c, false);  // v_dot2_f32_f16
}
#else
__device__ __forceinline__ float dot2(v2h a, v2h b, float c) {
  return fmaf((float)a.x, (float)b.x, fmaf((float)a.y, (float)b.y, c));
}
#endif

// W[ic][id][k] (f32) -> Wth[ic][k][id] (f16), 65536 elements
__global__ __launch_bounds__(256) void wt_kernel(const float* __restrict__ W,
                                                 _Float16* __restrict__ Wth) {
  int o  = blockIdx.x * 256 + threadIdx.x;
  int ic = o >> 11;
  int k  = (o >> 3) & 255;
  int id = o & 7;
  Wth[o] = (_Float16)W[(ic * 8 + id) * 256 + k];
}

// x (f32, 2M elems) -> xh (f16), same layout; 8 elems/thread
__global__ __launch_bounds__(256) void xh_kernel(const float* __restrict__ x,
                                                 _Float16* __restrict__ xh) {
  int tid = blockIdx.x * 256 + threadIdx.x;
  const float4* xp = (const float4*)x + tid * 2;
  float4 f0 = xp[0], f1 = xp[1];
  v2h h0 = {(_Float16)f0.x, (_Float16)f0.y};
  v2h h1 = {(_Float16)f0.z, (_Float16)f0.w};
  v2h h2 = {(_Float16)f1.x, (_Float16)f1.y};
  v2h h3 = {(_Float16)f1.z, (_Float16)f1.w};
  uint4 o;
  o.x = __builtin_bit_cast(unsigned, h0);
  o.y = __builtin_bit_cast(unsigned, h1);
  o.z = __builtin_bit_cast(unsigned, h2);
  o.w = __builtin_bit_cast(unsigned, h3);
  ((uint4*)xh)[tid] = o;
}

// squash over the 16 dc lanes, both samples at once; DPP-only reduction.
__device__ __forceinline__ v2f squash2(v2f o) {
  v2f s2 = o * o;
  s2 += dpp2<0xB1>(s2);   // + lane^1
  s2 += dpp2<0x4E>(s2);   // + lane^2
  s2 += dpp2<0x141>(s2);  // + lane^7 (row_half_mirror)
  s2 += dpp2<0x140>(s2);  // + lane^15 (row_mirror)
  s2 += (v2f){1e-7f, 1e-7f};
  v2f sc;
  sc.x = s2.x * __builtin_amdgcn_rsqf(s2.x) * __builtin_amdgcn_rcpf(1.f + s2.x);
  sc.y = s2.y * __builtin_amdgcn_rsqf(s2.y) * __builtin_amdgcn_rcpf(1.f + s2.y);
  return o * sc;  // sqrt(s2)/(1+s2) * o
}

// b[nc][ic] (=/+=) sum_dc v*uh[ic], both samples packed, via butterfly
// transpose-reduction over the 16 dc lanes; lane dc lands ic = icb + dc.
// Levels 8/2/1 via DPP, level 4 via ds_swizzle.
template <bool ASSIGN>
__device__ __forceinline__ void b_update2(v2f v, const v2f* uh2, int dc,
                                          float* bp0, float* bp1) {
#pragma unroll
  for (int icb = 0; icb < 32; icb += 16) {
    v2f a[16];
#pragma unroll
    for (int j = 0; j < 16; ++j) a[j] = v * uh2[icb + j];  // pk_mul
    v2f b8[8];
    const bool u8 = (dc & 8) != 0;
#pragma unroll
    for (int j = 0; j < 8; ++j) {
      v2f send = u8 ? a[j] : a[j + 8];
      v2f recv = dpp2<0x128>(send);          // exchange with lane^8
      b8[j] = (u8 ? a[j + 8] : a[j]) + recv;
    }
    v2f c4[4];
    const bool u4 = (dc & 4) != 0;
#pragma unroll
    for (int j = 0; j < 4; ++j) {
      v2f send = u4 ? b8[j] : b8[j + 4];
      v2f recv = swz4_2(send);               // exchange with lane^4 (DS)
      c4[j] = (u4 ? b8[j + 4] : b8[j]) + recv;
    }
    v2f d2[2];
    const bool u2 = (dc & 2) != 0;
#pragma unroll
    for (int j = 0; j < 2; ++j) {
      v2f send = u2 ? c4[j] : c4[j + 2];
      v2f recv = dpp2<0x4E>(send);           // exchange with lane^2
      d2[j] = (u2 ? c4[j + 2] : c4[j]) + recv;
    }
    const bool u1 = (dc & 1) != 0;
    v2f send = u1 ? d2[0] : d2[1];
    v2f recv = dpp2<0xB1>(send);             // exchange with lane^1
    v2f e = (u1 ? d2[1] : d2[0]) + recv;
    if (ASSIGN) { bp0[icb + dc] = e.x;  bp1[icb + dc] = e.y; }
    else        { bp0[icb + dc] += e.x; bp1[icb + dc] += e.y; }
  }
}

__global__ __launch_bounds__(256, 3) void caps_kernel(const _Float16* __restrict__ xh,
                                                      const uint4* __restrict__ Wt4,
                                                      float* __restrict__ out) {
  const int t  = threadIdx.x;
  const int nc = t >> 4;
  const int dc = t & 15;
  const int s0 = blockIdx.x * S;

  __shared__ float b_lds[S][16][33];             // +1 pad: nc-column reads conflict-free
  __shared__ __align__(16) float c_lds[16][68];  // c[n][2*ic+s]; 68: 16q -> 2-way max

  v2f uh2[32];
  v2f o2 = (v2f){0.f, 0.f};

  // ---- u_hat: uh2[ic] = {dot(u_s0, W), dot(u_s1, W)}; round-0 sum fused ----
  const v2h* xp0 = (const v2h*)(xh + (s0 + 0) * 256);  // block-uniform -> s_load
  const v2h* xp1 = (const v2h*)(xh + (s0 + 1) * 256);
#pragma unroll
  for (int ic = 0; ic < 32; ++ic) {
    uint4 wv = Wt4[ic * 256 + t];  // 8 f16 weights, one coalesced dwordx4
    v2h w0 = __builtin_bit_cast(v2h, wv.x);
    v2h w1 = __builtin_bit_cast(v2h, wv.y);
    v2h w2 = __builtin_bit_cast(v2h, wv.z);
    v2h w3 = __builtin_bit_cast(v2h, wv.w);
    float a0 = dot2(xp0[ic * 4 + 3], w3,
               dot2(xp0[ic * 4 + 2], w2,
               dot2(xp0[ic * 4 + 1], w1,
               dot2(xp0[ic * 4 + 0], w0, 0.f))));
    float a1 = dot2(xp1[ic * 4 + 3], w3,
               dot2(xp1[ic * 4 + 2], w2,
               dot2(xp1[ic * 4 + 1], w1,
               dot2(xp1[ic * 4 + 0], w0, 0.f))));
    v2f u = (v2f){a0, a1};
    uh2[ic] = u;
    o2 += u;
  }

  // ---- routing round 0: b = 0 => c = 1/16 ----
  {
    v2f v = squash2(o2 * (v2f){0.0625f, 0.0625f});
    b_update2<true>(v, uh2, dc, &b_lds[0][nc][0], &b_lds[1][nc][0]);
  }
  __syncthreads();

  // ---- rounds 1, 2 ----
#pragma unroll
  for (int r = 1; r < 3; ++r) {
    {  // distributed softmax over nc: all 256 threads. thread -> (s, ic, quarter)
      const int ss  = t >> 7;         // sample
      const int icc = (t >> 2) & 31;  // column
      const int q   = t & 3;          // rows 4q..4q+3
      // no max-subtraction: |b| is bounded far below exp overflow, and
      // softmax is shift-invariant.
      float e0 = __expf(b_lds[ss][4 * q + 0][icc]);
      float e1 = __expf(b_lds[ss][4 * q + 1][icc]);
      float e2 = __expf(b_lds[ss][4 * q + 2][icc]);
      float e3 = __expf(b_lds[ss][4 * q + 3][icc]);
      float ps = (e0 + e1) + (e2 + e3);
      ps += dppf<0xB1>(ps);  // + lane^1 (quad)
      ps += dppf<0x4E>(ps);  // + lane^2 (quad) -> full 16-row sum
      float inv = __builtin_amdgcn_rcpf(ps);
      c_lds[4 * q + 0][2 * icc + ss] = e0 * inv;
      c_lds[4 * q + 1][2 * icc + ss] = e1 * inv;
      c_lds[4 * q + 2][2 * icc + ss] = e2 * inv;
      c_lds[4 * q + 3][2 * icc + ss] = e3 * inv;
    }
    __syncthreads();

    const float4* cp = (const float4*)&c_lds[nc][0];  // {c0[2j],c1[2j],c0[2j+1],c1[2j+1]}
    v2f o = (v2f){0.f, 0.f};
#pragma unroll
    for (int j = 0; j < 16; ++j) {
      float4 cc = cp[j];
      o = __builtin_elementwise_fma((v2f){cc.x, cc.y}, uh2[2 * j + 0], o);
      o = __builtin_elementwise_fma((v2f){cc.z, cc.w}, uh2[2 * j + 1], o);
    }
    v2f v = squash2(o);
    if (r == 2) {
      out[(s0 + 0) * 256 + t] = v.x;
      out[(s0 + 1) * 256 + t] = v.y;
    } else {
      b_update2<false>(v, uh2, dc, &b_lds[0][nc][0], &b_lds[1][nc][0]);
    }
    __syncthreads();  // b complete before round-2 softmax; c safe to overwrite
  }
}

extern "C" void kernel_launch(void* const* d_in, const int* in_sizes, int n_in,
                              void* d_out, int out_size, void* d_ws, size_t ws_size,
                              hipStream_t stream) {
  const float* x = (const float*)d_in[0];
  const float* W = (const float*)d_in[1];
  _Float16* Wth = (_Float16*)d_ws;           // 128 KB: f16 W-transpose
  _Float16* xh  = (_Float16*)d_ws + 65536;   // 4 MB: f16 x

  wt_kernel<<<256, 256, 0, stream>>>(W, Wth);
  xh_kernel<<<1024, 256, 0, stream>>>(x, xh);
  caps_kernel<<<8192 / S, 256, 0, stream>>>(xh, (const uint4*)Wth, (float*)d_out);
}